// Round 5
// baseline (2586.904 us; speedup 1.0000x reference)
//
#include <hip/hip_runtime.h>
#include <math.h>

// Problem constants (fixed by the reference)
#define NN 10000
#define EE 160000
#define FF 128
#define RR 20
#define LL 3
#define CUTOFF 3.0f
#define F3 384           // 3*F
#define PI_F 3.14159265358979323846f

// Inline FMA macro — MUST stay a macro: a helper taking `float acc[16]`
// decays to a pointer, blocks SROA, and sends accumulators to scratch
// (measured: VGPR=52, VALUBusy 4.4%, 22x slowdown in round 2/4).
#define FMA16(ACC, A, W0, W1, W2, W3)                                     \
    ACC[0]  += (A) * (W0).x; ACC[1]  += (A) * (W0).y;                     \
    ACC[2]  += (A) * (W0).z; ACC[3]  += (A) * (W0).w;                     \
    ACC[4]  += (A) * (W1).x; ACC[5]  += (A) * (W1).y;                     \
    ACC[6]  += (A) * (W1).z; ACC[7]  += (A) * (W1).w;                     \
    ACC[8]  += (A) * (W2).x; ACC[9]  += (A) * (W2).y;                     \
    ACC[10] += (A) * (W2).z; ACC[11] += (A) * (W2).w;                     \
    ACC[12] += (A) * (W3).x; ACC[13] += (A) * (W3).y;                     \
    ACC[14] += (A) * (W3).z; ACC[15] += (A) * (W3).w;

// ---------------------------------------------------------------------------
// init: sfeat = emb[z], v = 0, deg = 0
__global__ __launch_bounds__(256) void k_init(const int* __restrict__ z,
                                              const float* __restrict__ emb,
                                              float* __restrict__ sfeat,
                                              float* __restrict__ v,
                                              int* __restrict__ deg) {
    int idx = blockIdx.x * 256 + threadIdx.x;
    if (idx < NN * 3 * FF) v[idx] = 0.f;
    if (idx < NN * FF) {
        int n = idx >> 7, f = idx & 127;
        sfeat[idx] = emb[z[n] * FF + f];
    }
    if (idx < NN) deg[idx] = 0;
}

// ---------------------------------------------------------------------------
// CSR build: count, exclusive-scan (single block), fill
__global__ __launch_bounds__(256) void k_count(const int* __restrict__ idx_i,
                                               int* __restrict__ deg) {
    int e = blockIdx.x * 256 + threadIdx.x;
    if (e < EE) atomicAdd(&deg[idx_i[e]], 1);
}

__global__ __launch_bounds__(1024) void k_scan(const int* __restrict__ deg,
                                               int* __restrict__ rowstart,
                                               int* __restrict__ cursor) {
    __shared__ int sd[1024];
    __shared__ int carry;
    if (threadIdx.x == 0) carry = 0;
    __syncthreads();
    for (int base = 0; base < NN; base += 1024) {
        int i = base + (int)threadIdx.x;
        int val = (i < NN) ? deg[i] : 0;
        sd[threadIdx.x] = val;
        __syncthreads();
        for (int off = 1; off < 1024; off <<= 1) {
            int t = (threadIdx.x >= off) ? sd[threadIdx.x - off] : 0;
            __syncthreads();
            sd[threadIdx.x] += t;
            __syncthreads();
        }
        if (i < NN) {
            int ex = carry + sd[threadIdx.x] - val;   // exclusive prefix
            rowstart[i] = ex;
            cursor[i] = ex;
        }
        __syncthreads();
        if (threadIdx.x == 0) carry += sd[1023];
        __syncthreads();
    }
    if (threadIdx.x == 0) rowstart[NN] = carry;
}

__global__ __launch_bounds__(256) void k_fill(const int* __restrict__ idx_i,
                                              int* __restrict__ cursor,
                                              int* __restrict__ eids) {
    int e = blockIdx.x * 256 + threadIdx.x;
    if (e < EE) {
        int p = atomicAdd(&cursor[idx_i[e]], 1);
        eids[p] = e;
    }
}

// ---------------------------------------------------------------------------
// geometry per edge: dir[E,3], cut[E], rbf[E,R]
__global__ __launch_bounds__(256) void k_geom(const float* __restrict__ pos,
                                              const int* __restrict__ idx_i,
                                              const int* __restrict__ idx_j,
                                              float* __restrict__ dir,
                                              float* __restrict__ cutb,
                                              float* __restrict__ rbf) {
    int e = blockIdx.x * 256 + threadIdx.x;
    if (e >= EE) return;
    int i = idx_i[e], j = idx_j[e];
    float dx = pos[j * 3 + 0] - pos[i * 3 + 0];
    float dy = pos[j * 3 + 1] - pos[i * 3 + 1];
    float dz = pos[j * 3 + 2] - pos[i * 3 + 2];
    float sq = dx * dx + dy * dy + dz * dz;
    float dist = sq > 0.f ? sqrtf(sq) : 0.f;
    float inv = dist > 0.f ? 1.f / dist : 0.f;
    dir[e * 3 + 0] = dx * inv;
    dir[e * 3 + 1] = dy * inv;
    dir[e * 3 + 2] = dz * inv;
    cutb[e] = (dist < CUTOFF) ? 0.5f * (cosf(PI_F * dist / CUTOFF) + 1.f) : 0.f;
    float b = PI_F * dist / CUTOFF;
#pragma unroll
    for (int r = 0; r < RR; r++)
        rbf[e * RR + r] = sinf((float)(r + 1) * b) * inv;
}

// ---------------------------------------------------------------------------
// Generic fp32 GEMM: C[:, strip] = act(A_cat @ W + bias)
// A_cat rows = A[row,0:KA] ++ A2[row,0:KTOT-KA]  (A2 null iff KA==KTOT)
// block: 256 threads = 32 rows x 8 col-groups x 16 cols; grid (ceil(M/32), NOUT/128)
template <int KTOT, bool SILU>
__global__ __launch_bounds__(256, 4) void k_mlp(const float* __restrict__ A, int KA,
                                                const float* __restrict__ A2,
                                                const float* __restrict__ W,
                                                const float* __restrict__ bias,
                                                float* __restrict__ C, int M, int NOUT) {
    __shared__ float As[32 * (KTOT + 1)];
    const int tid = threadIdx.x;
    const int row0 = blockIdx.x * 32;
    const int K2 = KTOT - KA;
    for (int idx = tid; idx < 32 * KTOT; idx += 256) {
        int r = idx / KTOT, k = idx - r * KTOT;
        int row = row0 + r;
        float val = 0.f;
        if (row < M) val = (k < KA) ? A[(size_t)row * KA + k] : A2[(size_t)row * K2 + (k - KA)];
        As[r * (KTOT + 1) + k] = val;
    }
    __syncthreads();
    const int r = tid >> 3;
    const int c0 = blockIdx.y * 128 + (tid & 7) * 16;
    float acc[16];
    {
        const float4* b4 = reinterpret_cast<const float4*>(bias + c0);
        float4 b0 = b4[0], b1 = b4[1], b2 = b4[2], b3 = b4[3];
        acc[0] = b0.x; acc[1] = b0.y; acc[2]  = b0.z; acc[3]  = b0.w;
        acc[4] = b1.x; acc[5] = b1.y; acc[6]  = b1.z; acc[7]  = b1.w;
        acc[8] = b2.x; acc[9] = b2.y; acc[10] = b2.z; acc[11] = b2.w;
        acc[12] = b3.x; acc[13] = b3.y; acc[14] = b3.z; acc[15] = b3.w;
    }
    const float* as = &As[r * (KTOT + 1)];
    for (int k = 0; k < KTOT; k++) {
        float a = as[k];
        const float4* w4 = reinterpret_cast<const float4*>(W + (size_t)k * NOUT + c0);
        float4 w0 = w4[0], w1 = w4[1], w2 = w4[2], w3 = w4[3];
        FMA16(acc, a, w0, w1, w2, w3)
    }
    int row = row0 + r;
    if (row < M) {
        float4* crow = reinterpret_cast<float4*>(C + (size_t)row * NOUT + c0);
#pragma unroll
        for (int q = 0; q < 4; q++) {
            float4 o;
            float x0 = acc[q * 4 + 0], x1 = acc[q * 4 + 1];
            float x2 = acc[q * 4 + 2], x3 = acc[q * 4 + 3];
            if (SILU) {
                x0 = x0 / (1.f + expf(-x0)); x1 = x1 / (1.f + expf(-x1));
                x2 = x2 / (1.f + expf(-x2)); x3 = x3 / (1.f + expf(-x3));
            }
            o.x = x0; o.y = x1; o.z = x2; o.w = x3;
            crow[q] = o;
        }
    }
}

// ---------------------------------------------------------------------------
// Dual GEMM sharing one A-tile: CU = A@WU, CV = A@WV   (A [M,128], W [128,128])
// block: 256 threads = 32 rows x 8 col-groups; grid ceil(M/32)
__global__ __launch_bounds__(256, 4) void k_uv(const float* __restrict__ A,
                                               const float* __restrict__ WU,
                                               const float* __restrict__ WV,
                                               float* __restrict__ CU,
                                               float* __restrict__ CV, int M) {
    __shared__ float As[32 * 129];
    const int tid = threadIdx.x;
    const int row0 = blockIdx.x * 32;
    for (int idx = tid; idx < 32 * 128; idx += 256) {
        int r = idx >> 7, k = idx & 127;
        int row = row0 + r;
        As[r * 129 + k] = (row < M) ? A[(size_t)row * 128 + k] : 0.f;
    }
    __syncthreads();
    const int r = tid >> 3;
    const int c0 = (tid & 7) * 16;
    float aU[16] = {0.f, 0.f, 0.f, 0.f, 0.f, 0.f, 0.f, 0.f,
                    0.f, 0.f, 0.f, 0.f, 0.f, 0.f, 0.f, 0.f};
    float aV[16] = {0.f, 0.f, 0.f, 0.f, 0.f, 0.f, 0.f, 0.f,
                    0.f, 0.f, 0.f, 0.f, 0.f, 0.f, 0.f, 0.f};
    const float* as = &As[r * 129];
    for (int k = 0; k < 128; k++) {
        float a = as[k];
        const float4* u4 = reinterpret_cast<const float4*>(WU + k * 128 + c0);
        float4 u0 = u4[0], u1 = u4[1], u2 = u4[2], u3 = u4[3];
        FMA16(aU, a, u0, u1, u2, u3)
        const float4* v4 = reinterpret_cast<const float4*>(WV + k * 128 + c0);
        float4 v0 = v4[0], v1 = v4[1], v2 = v4[2], v3 = v4[3];
        FMA16(aV, a, v0, v1, v2, v3)
    }
    int row = row0 + r;
    if (row < M) {
        float4* cu = reinterpret_cast<float4*>(CU + (size_t)row * 128 + c0);
        float4* cv = reinterpret_cast<float4*>(CV + (size_t)row * 128 + c0);
#pragma unroll
        for (int q = 0; q < 4; q++) {
            float4 ou; ou.x = aU[q*4+0]; ou.y = aU[q*4+1]; ou.z = aU[q*4+2]; ou.w = aU[q*4+3];
            float4 ov; ov.x = aV[q*4+0]; ov.y = aV[q*4+1]; ov.z = aV[q*4+2]; ov.w = aV[q*4+3];
            cu[q] = ou; cv[q] = ov;
        }
    }
}

// ---------------------------------------------------------------------------
// Node-centric edge accumulation (no atomics). One wave per node, CSR edges.
__global__ __launch_bounds__(512) void k_edge_node(const int* __restrict__ rowstart,
                                                   const int* __restrict__ eids,
                                                   const int* __restrict__ idx_j,
                                                   const float* __restrict__ dir,
                                                   const float* __restrict__ cutb,
                                                   const float* __restrict__ rbf,
                                                   const float* __restrict__ phi,
                                                   const float* __restrict__ vold,
                                                   const float* __restrict__ rbf_w,
                                                   const float* __restrict__ rbf_b,
                                                   float* __restrict__ sfeat,
                                                   float* __restrict__ vnew) {
    __shared__ float sW[RR * F3 + F3];   // 8064 floats = 31.5 KB
    for (int idx = threadIdx.x; idx < RR * F3; idx += 512) sW[idx] = rbf_w[idx];
    for (int idx = threadIdx.x; idx < F3; idx += 512) sW[RR * F3 + idx] = rbf_b[idx];
    __syncthreads();
    const int wave = threadIdx.x >> 6, lane = threadIdx.x & 63;
    const int n = blockIdx.x * 8 + wave;       // grid covers exactly NN
    float as0 = 0.f, as1 = 0.f;
    float ad00 = 0.f, ad01 = 0.f, ad10 = 0.f, ad11 = 0.f, ad20 = 0.f, ad21 = 0.f;
    const int t1 = rowstart[n + 1];
    for (int t = rowstart[n]; t < t1; ++t) {
        const int e = eids[t];
        const float c = cutb[e];
        if (c == 0.f) continue;                // wave-uniform
        const int j = idx_j[e];
        const float d0 = dir[e * 3 + 0], d1 = dir[e * 3 + 1], d2 = dir[e * 3 + 2];
        float rb[RR];
#pragma unroll
        for (int rr = 0; rr < RR; rr++) rb[rr] = rbf[e * RR + rr];  // broadcast
        float pw[6];
#pragma unroll
        for (int cb = 0; cb < 6; cb++) {
            const int col = cb * 64 + lane;
            float w = sW[RR * F3 + col];
#pragma unroll
            for (int rr = 0; rr < RR; rr++) w += rb[rr] * sW[rr * F3 + col];
            pw[cb] = phi[(size_t)j * F3 + col] * (w * c);
        }
        as0 += pw[2]; as1 += pw[3];
        const float vj00 = vold[(size_t)j * F3 + 0 * FF + lane];
        const float vj01 = vold[(size_t)j * F3 + 0 * FF + 64 + lane];
        const float vj10 = vold[(size_t)j * F3 + 1 * FF + lane];
        const float vj11 = vold[(size_t)j * F3 + 1 * FF + 64 + lane];
        const float vj20 = vold[(size_t)j * F3 + 2 * FF + lane];
        const float vj21 = vold[(size_t)j * F3 + 2 * FF + 64 + lane];
        ad00 += vj00 * pw[0] + pw[4] * d0;  ad01 += vj01 * pw[1] + pw[5] * d0;
        ad10 += vj10 * pw[0] + pw[4] * d1;  ad11 += vj11 * pw[1] + pw[5] * d1;
        ad20 += vj20 * pw[0] + pw[4] * d2;  ad21 += vj21 * pw[1] + pw[5] * d2;
    }
    sfeat[n * FF + lane]      += as0;          // node owned by this wave: no atomics
    sfeat[n * FF + 64 + lane] += as1;
    vnew[(size_t)n * F3 + 0 * FF + lane]      = vold[(size_t)n * F3 + 0 * FF + lane]      + ad00;
    vnew[(size_t)n * F3 + 0 * FF + 64 + lane] = vold[(size_t)n * F3 + 0 * FF + 64 + lane] + ad01;
    vnew[(size_t)n * F3 + 1 * FF + lane]      = vold[(size_t)n * F3 + 1 * FF + lane]      + ad10;
    vnew[(size_t)n * F3 + 1 * FF + 64 + lane] = vold[(size_t)n * F3 + 1 * FF + 64 + lane] + ad11;
    vnew[(size_t)n * F3 + 2 * FF + lane]      = vold[(size_t)n * F3 + 2 * FF + lane]      + ad20;
    vnew[(size_t)n * F3 + 2 * FF + 64 + lane] = vold[(size_t)n * F3 + 2 * FF + 64 + lane] + ad21;
}

// ---------------------------------------------------------------------------
// per (n,g): vnorm = safe_norm(Vv[n,:,g]), dot = <Uv,Vv>
__global__ __launch_bounds__(256) void k_normdot(const float* __restrict__ Uv,
                                                 const float* __restrict__ Vv,
                                                 float* __restrict__ vnorm,
                                                 float* __restrict__ dotb) {
    int idx = blockIdx.x * 256 + threadIdx.x;
    if (idx >= NN * FF) return;
    int n = idx >> 7, g = idx & 127;
    const float* uv = Uv + (size_t)n * F3 + g;
    const float* vv = Vv + (size_t)n * F3 + g;
    float u0 = uv[0], u1 = uv[FF], u2 = uv[2 * FF];
    float w0 = vv[0], w1 = vv[FF], w2 = vv[2 * FF];
    float sq = w0 * w0 + w1 * w1 + w2 * w2;
    vnorm[idx] = sq > 0.f ? sqrtf(sq) : 0.f;
    dotb[idx] = u0 * w0 + u1 * w1 + u2 * w2;
}

// ---------------------------------------------------------------------------
// gated update: v[n,:,g] += Uv[n,:,g]*a_vv;  s[n,g] += a_ss + a_sv*dot
// a layout [N,384] = [a_vv | a_sv | a_ss]
__global__ __launch_bounds__(256) void k_update(const float* __restrict__ a,
                                                const float* __restrict__ Uv,
                                                const float* __restrict__ dotb,
                                                float* __restrict__ v,
                                                float* __restrict__ sfeat) {
    int idx = blockIdx.x * 256 + threadIdx.x;
    if (idx >= NN * FF) return;
    int n = idx >> 7, g = idx & 127;
    float avv = a[(size_t)n * F3 + g];
    float asv = a[(size_t)n * F3 + 128 + g];
    float ass = a[(size_t)n * F3 + 256 + g];
#pragma unroll
    for (int d = 0; d < 3; d++)
        v[(size_t)n * F3 + d * FF + g] += Uv[(size_t)n * F3 + d * FF + g] * avv;
    sfeat[idx] += ass + asv * dotb[idx];
}

// ---------------------------------------------------------------------------
// transpose internal v[N,3,F] -> output vfeat[N,F,3]
__global__ __launch_bounds__(256) void k_outv(const float* __restrict__ v,
                                              float* __restrict__ outv) {
    int idx = blockIdx.x * 256 + threadIdx.x;
    if (idx >= NN * FF * 3) return;
    int n = idx / F3;
    int rem = idx - n * F3;
    int f = rem / 3;
    int d = rem - f * 3;
    outv[idx] = v[n * F3 + d * FF + f];
}

// ---------------------------------------------------------------------------
extern "C" void kernel_launch(void* const* d_in, const int* in_sizes, int n_in,
                              void* d_out, int out_size, void* d_ws, size_t ws_size,
                              hipStream_t stream) {
    const int*   z      = (const int*)d_in[0];
    const float* pos    = (const float*)d_in[1];
    const int*   idx_i  = (const int*)d_in[2];
    const int*   idx_j  = (const int*)d_in[3];
    const float* emb    = (const float*)d_in[4];
    const float* msg_w1 = (const float*)d_in[5];
    const float* msg_b1 = (const float*)d_in[6];
    const float* msg_w2 = (const float*)d_in[7];
    const float* msg_b2 = (const float*)d_in[8];
    const float* rbf_w  = (const float*)d_in[9];
    const float* rbf_b  = (const float*)d_in[10];
    const float* upd_U  = (const float*)d_in[11];
    const float* upd_V  = (const float*)d_in[12];
    const float* upd_w1 = (const float*)d_in[13];
    const float* upd_b1 = (const float*)d_in[14];
    const float* upd_w2 = (const float*)d_in[15];
    const float* upd_b2 = (const float*)d_in[16];

    float* sfeat = (float*)d_out;            // [N,F]
    float* outv  = sfeat + NN * FF;          // [N,F,3]

    float* ws    = (float*)d_ws;
    float* va    = ws;                       // [N,3,F] ping
    float* vb    = va + NN * F3;             // [N,3,F] pong
    float* phi   = vb + NN * F3;             // [N,3F] (also reused as 'a')
    float* h     = phi + NN * F3;            // [N,F]
    float* Uvb   = h + NN * FF;              // [N,3,F]
    float* Vvb   = Uvb + NN * F3;            // [N,3,F]
    float* vnorm = Vvb + NN * F3;            // [N,F]
    float* dotb  = vnorm + NN * FF;          // [N,F]
    float* rbf   = dotb + NN * FF;           // [E,R]
    float* cutb  = rbf + EE * RR;            // [E]
    float* dirb  = cutb + EE;                // [E,3]
    int*   ib        = (int*)(dirb + EE * 3);
    int*   deg       = ib;                   // [N]
    int*   rowstart  = deg + NN;             // [N+1]
    int*   cursor    = rowstart + NN + 1;    // [N]
    int*   eids      = cursor + NN;          // [E]

    const dim3 blk(256);
    k_init<<<dim3((NN * 3 * FF) / 256), blk, 0, stream>>>(z, emb, sfeat, va, deg);
    k_count<<<dim3((EE + 255) / 256), blk, 0, stream>>>(idx_i, deg);
    k_scan<<<dim3(1), dim3(1024), 0, stream>>>(deg, rowstart, cursor);
    k_fill<<<dim3((EE + 255) / 256), blk, 0, stream>>>(idx_i, cursor, eids);
    k_geom<<<dim3((EE + 255) / 256), blk, 0, stream>>>(pos, idx_i, idx_j, dirb, cutb, rbf);

    float* vcur = va;
    float* vnxt = vb;
    const int gN  = (NN + 31) / 32;          // 313
    const int g3N = (3 * NN + 31) / 32;      // 938

    for (int l = 0; l < LL; l++) {
        const float* mw1 = msg_w1 + l * FF * FF;
        const float* mb1 = msg_b1 + l * FF;
        const float* mw2 = msg_w2 + l * FF * F3;
        const float* mb2 = msg_b2 + l * F3;
        const float* rw  = rbf_w + l * RR * F3;
        const float* rb  = rbf_b + l * F3;
        const float* uU  = upd_U + l * FF * FF;
        const float* uV  = upd_V + l * FF * FF;
        const float* uw1 = upd_w1 + l * 2 * FF * FF;
        const float* ub1 = upd_b1 + l * FF;
        const float* uw2 = upd_w2 + l * FF * F3;
        const float* ub2 = upd_b2 + l * F3;

        // h = silu(s@w1+b1); phi = h@w2+b2
        k_mlp<128, true><<<dim3(gN, 1), blk, 0, stream>>>(sfeat, 128, nullptr, mw1, mb1, h, NN, 128);
        k_mlp<128, false><<<dim3(gN, 3), blk, 0, stream>>>(h, 128, nullptr, mw2, mb2, phi, NN, F3);

        // node-centric message aggregation: sfeat += ..., vnxt = vcur + dv
        k_edge_node<<<dim3(NN / 8), dim3(512), 0, stream>>>(rowstart, eids, idx_j, dirb,
                                                            cutb, rbf, phi, vcur, rw, rb,
                                                            sfeat, vnxt);

        // Uv/Vv dual GEMM on vnxt
        k_uv<<<dim3(g3N), blk, 0, stream>>>(vnxt, uU, uV, Uvb, Vvb, 3 * NN);
        k_normdot<<<dim3((NN * FF) / 256), blk, 0, stream>>>(Uvb, Vvb, vnorm, dotb);

        // h = silu([vnorm|sfeat]@w1+b1); a = h@w2+b2 (into phi buffer)
        k_mlp<256, true><<<dim3(gN, 1), blk, 0, stream>>>(vnorm, 128, sfeat, uw1, ub1, h, NN, 128);
        k_mlp<128, false><<<dim3(gN, 3), blk, 0, stream>>>(h, 128, nullptr, uw2, ub2, phi, NN, F3);

        // gating epilogue (updates vnxt, sfeat)
        k_update<<<dim3((NN * FF) / 256), blk, 0, stream>>>(phi, Uvb, dotb, vnxt, sfeat);

        // ping-pong
        float* tmp = vcur; vcur = vnxt; vnxt = tmp;
    }

    k_outv<<<dim3((NN * FF * 3 + 255) / 256), blk, 0, stream>>>(vcur, outv);
}

// Round 6
// 987.948 us; speedup vs baseline: 2.6185x; 2.6185x over previous
//
#include <hip/hip_runtime.h>
#include <math.h>

// Problem constants (fixed by the reference)
#define NN 10000
#define EE 160000
#define FF 128
#define RR 20
#define LL 3
#define CUTOFF 3.0f
#define F3 384           // 3*F
#define PI_F 3.14159265358979323846f

// NOTE (round 4 lesson): never pass accumulator arrays to helper functions —
// array params decay to pointers, block SROA, accumulators land in scratch
// (VGPR=52, 22x slowdown). All inner loops are fully unrolled with static
// indices so everything stays in registers.

// ---------------------------------------------------------------------------
// init: sfeat = emb[z], v = 0, deg = 0
__global__ __launch_bounds__(256) void k_init(const int* __restrict__ z,
                                              const float* __restrict__ emb,
                                              float* __restrict__ sfeat,
                                              float* __restrict__ v,
                                              int* __restrict__ deg) {
    int idx = blockIdx.x * 256 + threadIdx.x;
    if (idx < NN * 3 * FF) v[idx] = 0.f;
    if (idx < NN * FF) {
        int n = idx >> 7, f = idx & 127;
        sfeat[idx] = emb[z[n] * FF + f];
    }
    if (idx < NN) deg[idx] = 0;
}

// ---------------------------------------------------------------------------
// geometry per edge: dir[E,3], cut[E], rbf[E,R]
__global__ __launch_bounds__(256) void k_geom(const float* __restrict__ pos,
                                              const int* __restrict__ idx_i,
                                              const int* __restrict__ idx_j,
                                              float* __restrict__ dir,
                                              float* __restrict__ cutb,
                                              float* __restrict__ rbf) {
    int e = blockIdx.x * 256 + threadIdx.x;
    if (e >= EE) return;
    int i = idx_i[e], j = idx_j[e];
    float dx = pos[j * 3 + 0] - pos[i * 3 + 0];
    float dy = pos[j * 3 + 1] - pos[i * 3 + 1];
    float dz = pos[j * 3 + 2] - pos[i * 3 + 2];
    float sq = dx * dx + dy * dy + dz * dz;
    float dist = sq > 0.f ? sqrtf(sq) : 0.f;
    float inv = dist > 0.f ? 1.f / dist : 0.f;
    dir[e * 3 + 0] = dx * inv;
    dir[e * 3 + 1] = dy * inv;
    dir[e * 3 + 2] = dz * inv;
    cutb[e] = (dist < CUTOFF) ? 0.5f * (cosf(PI_F * dist / CUTOFF) + 1.f) : 0.f;
    float b = PI_F * dist / CUTOFF;
#pragma unroll
    for (int r = 0; r < RR; r++)
        rbf[e * RR + r] = sinf((float)(r + 1) * b) * inv;
}

// ---------------------------------------------------------------------------
// CSR build over LIVE edges only (cut > 0): count, scan, fill
__global__ __launch_bounds__(256) void k_count(const int* __restrict__ idx_i,
                                               const float* __restrict__ cutb,
                                               int* __restrict__ deg) {
    int e = blockIdx.x * 256 + threadIdx.x;
    if (e < EE && cutb[e] > 0.f) atomicAdd(&deg[idx_i[e]], 1);
}

__global__ __launch_bounds__(1024) void k_scan(const int* __restrict__ deg,
                                               int* __restrict__ rowstart,
                                               int* __restrict__ cursor) {
    __shared__ int sd[1024];
    __shared__ int carry;
    if (threadIdx.x == 0) carry = 0;
    __syncthreads();
    for (int base = 0; base < NN; base += 1024) {
        int i = base + (int)threadIdx.x;
        int val = (i < NN) ? deg[i] : 0;
        sd[threadIdx.x] = val;
        __syncthreads();
        for (int off = 1; off < 1024; off <<= 1) {
            int t = (threadIdx.x >= off) ? sd[threadIdx.x - off] : 0;
            __syncthreads();
            sd[threadIdx.x] += t;
            __syncthreads();
        }
        if (i < NN) {
            int ex = carry + sd[threadIdx.x] - val;   // exclusive prefix
            rowstart[i] = ex;
            cursor[i] = ex;
        }
        __syncthreads();
        if (threadIdx.x == 0) carry += sd[1023];
        __syncthreads();
    }
    if (threadIdx.x == 0) rowstart[NN] = carry;
}

__global__ __launch_bounds__(256) void k_fill(const int* __restrict__ idx_i,
                                              const float* __restrict__ cutb,
                                              int* __restrict__ cursor,
                                              int* __restrict__ eids) {
    int e = blockIdx.x * 256 + threadIdx.x;
    if (e < EE && cutb[e] > 0.f) {
        int p = atomicAdd(&cursor[idx_i[e]], 1);
        eids[p] = e;
    }
}

// ---------------------------------------------------------------------------
// Generic fp32 GEMM, register-tiled. C[:, strip] = act(A_cat @ W + bias)
// A_cat rows = A[row,0:KA] ++ A2[row,0:KTOT-KA]  (A2 null iff KA==KTOT)
// Tile: RTILE rows x 128 cols per block (256 thr). Thread: RT=RTILE/8 rows x 4 cols.
// LDS is K-major (As[k][r], stride RTILE+4) so the per-k A read is ds_read_b128.
// Per k-step/thread: 1 weight float4 (wave-coherent, 2x redundancy) + RT/4 b128
// A reads + 4*RT FMAs -> VALU-bound (round-5 version was L1-bound at 6% VALU).
template <int KTOT, int RTILE, bool SILU>
__global__ __launch_bounds__(256, 4) void k_mlp(const float* __restrict__ A, int KA,
                                                const float* __restrict__ A2,
                                                const float* __restrict__ W,
                                                const float* __restrict__ bias,
                                                float* __restrict__ C, int M, int NOUT) {
    constexpr int RT = RTILE / 8;        // rows per thread
    constexpr int STR = RTILE + 4;       // LDS stride (words): aligned, 4-way max
    __shared__ float As[KTOT * STR];
    const int tid = threadIdx.x;
    const int row0 = blockIdx.x * RTILE;
    const int K2 = KTOT - KA;
    for (int idx = tid; idx < RTILE * KTOT; idx += 256) {
        int r = idx / KTOT, k = idx - r * KTOT;    // row-major: coalesced global read
        int row = row0 + r;
        float val = 0.f;
        if (row < M) val = (k < KA) ? A[(size_t)row * KA + k] : A2[(size_t)row * K2 + (k - KA)];
        As[k * STR + r] = val;                     // K-major LDS write
    }
    __syncthreads();
    const int cg = tid & 31;             // col group: 4 cols
    const int rg = tid >> 5;             // row group: RT rows
    const int c0 = blockIdx.y * 128 + cg * 4;
    const int r0 = rg * RT;
    float4 acc[RT];
    float4 binit = bias ? *reinterpret_cast<const float4*>(bias + c0)
                        : make_float4(0.f, 0.f, 0.f, 0.f);
#pragma unroll
    for (int p = 0; p < RT; p++) acc[p] = binit;
    for (int k = 0; k < KTOT; k++) {
        float4 w = *reinterpret_cast<const float4*>(W + (size_t)k * NOUT + c0);
        const float* ap = &As[k * STR + r0];
        float av[RT];
        float4 a0 = *reinterpret_cast<const float4*>(ap);
        av[0] = a0.x; av[1] = a0.y; av[2] = a0.z; av[3] = a0.w;
        if constexpr (RT == 8) {
            float4 a1 = *reinterpret_cast<const float4*>(ap + 4);
            av[4] = a1.x; av[5] = a1.y; av[6] = a1.z; av[7] = a1.w;
        }
#pragma unroll
        for (int p = 0; p < RT; p++) {
            acc[p].x += av[p] * w.x; acc[p].y += av[p] * w.y;
            acc[p].z += av[p] * w.z; acc[p].w += av[p] * w.w;
        }
    }
#pragma unroll
    for (int p = 0; p < RT; p++) {
        int row = row0 + r0 + p;
        if (row < M) {
            float4 o = acc[p];
            if (SILU) {
                o.x = o.x / (1.f + expf(-o.x)); o.y = o.y / (1.f + expf(-o.y));
                o.z = o.z / (1.f + expf(-o.z)); o.w = o.w / (1.f + expf(-o.w));
            }
            *reinterpret_cast<float4*>(C + (size_t)row * NOUT + c0) = o;
        }
    }
}

// ---------------------------------------------------------------------------
// Dual GEMM sharing one A-tile: CU = A@WU, CV = A@WV  (A [M,128], W [128,128])
// Same register tiling as k_mlp with RTILE=64; 64 accumulators.
__global__ __launch_bounds__(256, 2) void k_uv(const float* __restrict__ A,
                                               const float* __restrict__ WU,
                                               const float* __restrict__ WV,
                                               float* __restrict__ CU,
                                               float* __restrict__ CV, int M) {
    constexpr int STR = 68;
    __shared__ float As[128 * STR];
    const int tid = threadIdx.x;
    const int row0 = blockIdx.x * 64;
    for (int idx = tid; idx < 64 * 128; idx += 256) {
        int r = idx >> 7, k = idx & 127;
        int row = row0 + r;
        As[k * STR + r] = (row < M) ? A[(size_t)row * 128 + k] : 0.f;
    }
    __syncthreads();
    const int cg = tid & 31, rg = tid >> 5;
    const int c0 = cg * 4;
    const int r0 = rg * 8;
    float4 aU[8], aV[8];
#pragma unroll
    for (int p = 0; p < 8; p++) {
        aU[p] = make_float4(0.f, 0.f, 0.f, 0.f);
        aV[p] = make_float4(0.f, 0.f, 0.f, 0.f);
    }
    for (int k = 0; k < 128; k++) {
        float4 wu = *reinterpret_cast<const float4*>(WU + k * 128 + c0);
        float4 wv = *reinterpret_cast<const float4*>(WV + k * 128 + c0);
        const float* ap = &As[k * STR + r0];
        float4 a0 = *reinterpret_cast<const float4*>(ap);
        float4 a1 = *reinterpret_cast<const float4*>(ap + 4);
        float av[8];
        av[0] = a0.x; av[1] = a0.y; av[2] = a0.z; av[3] = a0.w;
        av[4] = a1.x; av[5] = a1.y; av[6] = a1.z; av[7] = a1.w;
#pragma unroll
        for (int p = 0; p < 8; p++) {
            aU[p].x += av[p] * wu.x; aU[p].y += av[p] * wu.y;
            aU[p].z += av[p] * wu.z; aU[p].w += av[p] * wu.w;
            aV[p].x += av[p] * wv.x; aV[p].y += av[p] * wv.y;
            aV[p].z += av[p] * wv.z; aV[p].w += av[p] * wv.w;
        }
    }
#pragma unroll
    for (int p = 0; p < 8; p++) {
        int row = row0 + r0 + p;
        if (row < M) {
            *reinterpret_cast<float4*>(CU + (size_t)row * 128 + c0) = aU[p];
            *reinterpret_cast<float4*>(CV + (size_t)row * 128 + c0) = aV[p];
        }
    }
}

// ---------------------------------------------------------------------------
// Node-centric edge accumulation (no atomics). One wave per node, CSR holds
// only live (cut>0) edges. Edges processed 2 at a time so each LDS weight
// read feeds 2 FMAs.
__global__ __launch_bounds__(512) void k_edge_node(const int* __restrict__ rowstart,
                                                   const int* __restrict__ eids,
                                                   const int* __restrict__ idx_j,
                                                   const float* __restrict__ dir,
                                                   const float* __restrict__ cutb,
                                                   const float* __restrict__ rbf,
                                                   const float* __restrict__ phi,
                                                   const float* __restrict__ vold,
                                                   const float* __restrict__ rbf_w,
                                                   const float* __restrict__ rbf_b,
                                                   float* __restrict__ sfeat,
                                                   float* __restrict__ vnew) {
    __shared__ float sW[RR * F3 + F3];   // weights then bias: 31.5 KB
    for (int idx = threadIdx.x; idx < RR * F3; idx += 512) sW[idx] = rbf_w[idx];
    for (int idx = threadIdx.x; idx < F3; idx += 512) sW[RR * F3 + idx] = rbf_b[idx];
    __syncthreads();
    const int wave = threadIdx.x >> 6, lane = threadIdx.x & 63;
    const int n = blockIdx.x * 8 + wave;       // grid covers exactly NN
    float as0 = 0.f, as1 = 0.f;
    float ad00 = 0.f, ad01 = 0.f, ad10 = 0.f, ad11 = 0.f, ad20 = 0.f, ad21 = 0.f;
    int t = rowstart[n];
    const int t1 = rowstart[n + 1];
    for (; t + 1 < t1; t += 2) {
        const int e0 = eids[t], e1 = eids[t + 1];
        const float cA = cutb[e0], cB = cutb[e1];
        const int j0 = idx_j[e0], j1 = idx_j[e1];
        const float dA0 = dir[e0 * 3 + 0], dA1 = dir[e0 * 3 + 1], dA2 = dir[e0 * 3 + 2];
        const float dB0 = dir[e1 * 3 + 0], dB1 = dir[e1 * 3 + 1], dB2 = dir[e1 * 3 + 2];
        float rb0[RR], rb1[RR];
#pragma unroll
        for (int rr = 0; rr < RR; rr++) {
            rb0[rr] = rbf[e0 * RR + rr];       // broadcast loads
            rb1[rr] = rbf[e1 * RR + rr];
        }
        float pw0[6], pw1[6];
#pragma unroll
        for (int cb = 0; cb < 6; cb++) {
            const int col = cb * 64 + lane;
            const float wb = sW[RR * F3 + col];
            float a0 = wb, a1 = wb;
#pragma unroll
            for (int rr = 0; rr < RR; rr++) {
                const float wv = sW[rr * F3 + col];
                a0 += rb0[rr] * wv; a1 += rb1[rr] * wv;
            }
            pw0[cb] = phi[(size_t)j0 * F3 + col] * (a0 * cA);
            pw1[cb] = phi[(size_t)j1 * F3 + col] * (a1 * cB);
        }
        as0 += pw0[2] + pw1[2];
        as1 += pw0[3] + pw1[3];
        ad00 += vold[(size_t)j0 * F3 + 0 * FF + lane]      * pw0[0] + pw0[4] * dA0
              + vold[(size_t)j1 * F3 + 0 * FF + lane]      * pw1[0] + pw1[4] * dB0;
        ad01 += vold[(size_t)j0 * F3 + 0 * FF + 64 + lane] * pw0[1] + pw0[5] * dA0
              + vold[(size_t)j1 * F3 + 0 * FF + 64 + lane] * pw1[1] + pw1[5] * dB0;
        ad10 += vold[(size_t)j0 * F3 + 1 * FF + lane]      * pw0[0] + pw0[4] * dA1
              + vold[(size_t)j1 * F3 + 1 * FF + lane]      * pw1[0] + pw1[4] * dB1;
        ad11 += vold[(size_t)j0 * F3 + 1 * FF + 64 + lane] * pw0[1] + pw0[5] * dA1
              + vold[(size_t)j1 * F3 + 1 * FF + 64 + lane] * pw1[1] + pw1[5] * dB1;
        ad20 += vold[(size_t)j0 * F3 + 2 * FF + lane]      * pw0[0] + pw0[4] * dA2
              + vold[(size_t)j1 * F3 + 2 * FF + lane]      * pw1[0] + pw1[4] * dB2;
        ad21 += vold[(size_t)j0 * F3 + 2 * FF + 64 + lane] * pw0[1] + pw0[5] * dA2
              + vold[(size_t)j1 * F3 + 2 * FF + 64 + lane] * pw1[1] + pw1[5] * dB2;
    }
    if (t < t1) {                              // odd remainder edge
        const int e = eids[t];
        const float cA = cutb[e];
        const int j = idx_j[e];
        const float d0 = dir[e * 3 + 0], d1 = dir[e * 3 + 1], d2 = dir[e * 3 + 2];
        float rb[RR];
#pragma unroll
        for (int rr = 0; rr < RR; rr++) rb[rr] = rbf[e * RR + rr];
        float pw[6];
#pragma unroll
        for (int cb = 0; cb < 6; cb++) {
            const int col = cb * 64 + lane;
            float w = sW[RR * F3 + col];
#pragma unroll
            for (int rr = 0; rr < RR; rr++) w += rb[rr] * sW[rr * F3 + col];
            pw[cb] = phi[(size_t)j * F3 + col] * (w * cA);
        }
        as0 += pw[2]; as1 += pw[3];
        ad00 += vold[(size_t)j * F3 + 0 * FF + lane]      * pw[0] + pw[4] * d0;
        ad01 += vold[(size_t)j * F3 + 0 * FF + 64 + lane] * pw[1] + pw[5] * d0;
        ad10 += vold[(size_t)j * F3 + 1 * FF + lane]      * pw[0] + pw[4] * d1;
        ad11 += vold[(size_t)j * F3 + 1 * FF + 64 + lane] * pw[1] + pw[5] * d1;
        ad20 += vold[(size_t)j * F3 + 2 * FF + lane]      * pw[0] + pw[4] * d2;
        ad21 += vold[(size_t)j * F3 + 2 * FF + 64 + lane] * pw[1] + pw[5] * d2;
    }
    sfeat[n * FF + lane]      += as0;          // node owned by this wave: no atomics
    sfeat[n * FF + 64 + lane] += as1;
    vnew[(size_t)n * F3 + 0 * FF + lane]      = vold[(size_t)n * F3 + 0 * FF + lane]      + ad00;
    vnew[(size_t)n * F3 + 0 * FF + 64 + lane] = vold[(size_t)n * F3 + 0 * FF + 64 + lane] + ad01;
    vnew[(size_t)n * F3 + 1 * FF + lane]      = vold[(size_t)n * F3 + 1 * FF + lane]      + ad10;
    vnew[(size_t)n * F3 + 1 * FF + 64 + lane] = vold[(size_t)n * F3 + 1 * FF + 64 + lane] + ad11;
    vnew[(size_t)n * F3 + 2 * FF + lane]      = vold[(size_t)n * F3 + 2 * FF + lane]      + ad20;
    vnew[(size_t)n * F3 + 2 * FF + 64 + lane] = vold[(size_t)n * F3 + 2 * FF + 64 + lane] + ad21;
}

// ---------------------------------------------------------------------------
// per (n,g): vnorm = safe_norm(Vv[n,:,g]), dot = <Uv,Vv>
__global__ __launch_bounds__(256) void k_normdot(const float* __restrict__ Uv,
                                                 const float* __restrict__ Vv,
                                                 float* __restrict__ vnorm,
                                                 float* __restrict__ dotb) {
    int idx = blockIdx.x * 256 + threadIdx.x;
    if (idx >= NN * FF) return;
    int n = idx >> 7, g = idx & 127;
    const float* uv = Uv + (size_t)n * F3 + g;
    const float* vv = Vv + (size_t)n * F3 + g;
    float u0 = uv[0], u1 = uv[FF], u2 = uv[2 * FF];
    float w0 = vv[0], w1 = vv[FF], w2 = vv[2 * FF];
    float sq = w0 * w0 + w1 * w1 + w2 * w2;
    vnorm[idx] = sq > 0.f ? sqrtf(sq) : 0.f;
    dotb[idx] = u0 * w0 + u1 * w1 + u2 * w2;
}

// ---------------------------------------------------------------------------
// gated update: v[n,:,g] += Uv[n,:,g]*a_vv;  s[n,g] += a_ss + a_sv*dot
// a layout [N,384] = [a_vv | a_sv | a_ss]
__global__ __launch_bounds__(256) void k_update(const float* __restrict__ a,
                                                const float* __restrict__ Uv,
                                                const float* __restrict__ dotb,
                                                float* __restrict__ v,
                                                float* __restrict__ sfeat) {
    int idx = blockIdx.x * 256 + threadIdx.x;
    if (idx >= NN * FF) return;
    int n = idx >> 7, g = idx & 127;
    float avv = a[(size_t)n * F3 + g];
    float asv = a[(size_t)n * F3 + 128 + g];
    float ass = a[(size_t)n * F3 + 256 + g];
#pragma unroll
    for (int d = 0; d < 3; d++)
        v[(size_t)n * F3 + d * FF + g] += Uv[(size_t)n * F3 + d * FF + g] * avv;
    sfeat[idx] += ass + asv * dotb[idx];
}

// ---------------------------------------------------------------------------
// transpose internal v[N,3,F] -> output vfeat[N,F,3]
__global__ __launch_bounds__(256) void k_outv(const float* __restrict__ v,
                                              float* __restrict__ outv) {
    int idx = blockIdx.x * 256 + threadIdx.x;
    if (idx >= NN * FF * 3) return;
    int n = idx / F3;
    int rem = idx - n * F3;
    int f = rem / 3;
    int d = rem - f * 3;
    outv[idx] = v[n * F3 + d * FF + f];
}

// ---------------------------------------------------------------------------
extern "C" void kernel_launch(void* const* d_in, const int* in_sizes, int n_in,
                              void* d_out, int out_size, void* d_ws, size_t ws_size,
                              hipStream_t stream) {
    const int*   z      = (const int*)d_in[0];
    const float* pos    = (const float*)d_in[1];
    const int*   idx_i  = (const int*)d_in[2];
    const int*   idx_j  = (const int*)d_in[3];
    const float* emb    = (const float*)d_in[4];
    const float* msg_w1 = (const float*)d_in[5];
    const float* msg_b1 = (const float*)d_in[6];
    const float* msg_w2 = (const float*)d_in[7];
    const float* msg_b2 = (const float*)d_in[8];
    const float* rbf_w  = (const float*)d_in[9];
    const float* rbf_b  = (const float*)d_in[10];
    const float* upd_U  = (const float*)d_in[11];
    const float* upd_V  = (const float*)d_in[12];
    const float* upd_w1 = (const float*)d_in[13];
    const float* upd_b1 = (const float*)d_in[14];
    const float* upd_w2 = (const float*)d_in[15];
    const float* upd_b2 = (const float*)d_in[16];

    float* sfeat = (float*)d_out;            // [N,F]
    float* outv  = sfeat + NN * FF;          // [N,F,3]

    float* ws    = (float*)d_ws;
    float* va    = ws;                       // [N,3,F] ping
    float* vb    = va + NN * F3;             // [N,3,F] pong
    float* phi   = vb + NN * F3;             // [N,3F] (also reused as 'a')
    float* h     = phi + NN * F3;            // [N,F]
    float* Uvb   = h + NN * FF;              // [N,3,F]
    float* Vvb   = Uvb + NN * F3;            // [N,3,F]
    float* vnorm = Vvb + NN * F3;            // [N,F]
    float* dotb  = vnorm + NN * FF;          // [N,F]
    float* rbf   = dotb + NN * FF;           // [E,R]
    float* cutb  = rbf + EE * RR;            // [E]
    float* dirb  = cutb + EE;                // [E,3]
    int*   ib        = (int*)(dirb + EE * 3);
    int*   deg       = ib;                   // [N]
    int*   rowstart  = deg + NN;             // [N+1]
    int*   cursor    = rowstart + NN + 1;    // [N]
    int*   eids      = cursor + NN;          // [E]

    const dim3 blk(256);
    k_init<<<dim3((NN * 3 * FF) / 256), blk, 0, stream>>>(z, emb, sfeat, va, deg);
    k_geom<<<dim3((EE + 255) / 256), blk, 0, stream>>>(pos, idx_i, idx_j, dirb, cutb, rbf);
    k_count<<<dim3((EE + 255) / 256), blk, 0, stream>>>(idx_i, cutb, deg);
    k_scan<<<dim3(1), dim3(1024), 0, stream>>>(deg, rowstart, cursor);
    k_fill<<<dim3((EE + 255) / 256), blk, 0, stream>>>(idx_i, cutb, cursor, eids);

    float* vcur = va;
    float* vnxt = vb;
    const int gN64  = (NN + 63) / 64;        // 157
    const int gN32  = (NN + 31) / 32;        // 313
    const int g3N64 = (3 * NN + 63) / 64;    // 469

    for (int l = 0; l < LL; l++) {
        const float* mw1 = msg_w1 + l * FF * FF;
        const float* mb1 = msg_b1 + l * FF;
        const float* mw2 = msg_w2 + l * FF * F3;
        const float* mb2 = msg_b2 + l * F3;
        const float* rw  = rbf_w + l * RR * F3;
        const float* rb  = rbf_b + l * F3;
        const float* uU  = upd_U + l * FF * FF;
        const float* uV  = upd_V + l * FF * FF;
        const float* uw1 = upd_w1 + l * 2 * FF * FF;
        const float* ub1 = upd_b1 + l * FF;
        const float* uw2 = upd_w2 + l * FF * F3;
        const float* ub2 = upd_b2 + l * F3;

        // h = silu(s@w1+b1); phi = h@w2+b2
        k_mlp<128, 64, true><<<dim3(gN64, 1), blk, 0, stream>>>(sfeat, 128, nullptr, mw1, mb1, h, NN, 128);
        k_mlp<128, 64, false><<<dim3(gN64, 3), blk, 0, stream>>>(h, 128, nullptr, mw2, mb2, phi, NN, F3);

        // node-centric message aggregation: sfeat += ..., vnxt = vcur + dv
        k_edge_node<<<dim3(NN / 8), dim3(512), 0, stream>>>(rowstart, eids, idx_j, dirb,
                                                            cutb, rbf, phi, vcur, rw, rb,
                                                            sfeat, vnxt);

        // Uv/Vv dual GEMM on vnxt
        k_uv<<<dim3(g3N64), blk, 0, stream>>>(vnxt, uU, uV, Uvb, Vvb, 3 * NN);
        k_normdot<<<dim3((NN * FF) / 256), blk, 0, stream>>>(Uvb, Vvb, vnorm, dotb);

        // h = silu([vnorm|sfeat]@w1+b1); a = h@w2+b2 (into phi buffer)
        k_mlp<256, 32, true><<<dim3(gN32, 1), blk, 0, stream>>>(vnorm, 128, sfeat, uw1, ub1, h, NN, 128);
        k_mlp<128, 64, false><<<dim3(gN64, 3), blk, 0, stream>>>(h, 128, nullptr, uw2, ub2, phi, NN, F3);

        // gating epilogue (updates vnxt, sfeat)
        k_update<<<dim3((NN * FF) / 256), blk, 0, stream>>>(phi, Uvb, dotb, vnxt, sfeat);

        // ping-pong
        float* tmp = vcur; vcur = vnxt; vnxt = tmp;
    }

    k_outv<<<dim3((NN * FF * 3 + 255) / 256), blk, 0, stream>>>(vcur, outv);
}